// Round 7
// baseline (105.382 us; speedup 1.0000x reference)
//
#include <hip/hip_runtime.h>
#include <hip/hip_fp16.h>

typedef _Float16 half8_t __attribute__((ext_vector_type(8)));
typedef _Float16 half4_t __attribute__((ext_vector_type(4)));
typedef _Float16 half2_t __attribute__((ext_vector_type(2)));
typedef float f32x4 __attribute__((ext_vector_type(4)));
typedef unsigned int u32x4 __attribute__((ext_vector_type(4)));

// ws: [0,55296)      w1T fp16 [288][96]; rows 0..95 = Q cols PERMUTED (row f*16+m ->
//                    Q col (f>>1)*32+(m>>2)*8+(f&1)*4+(m&3)), scaled by qs*log2e;
//                    rows 96..287 = K,V cols (plain order, unscaled)
//     [55296,73728)  w2T fp16 [96][96]
//     [73728,74880)  b1p f32 [288] (orig col order; Q entries scaled by qs*log2e)
//     [74880,140416) tblP f32 [4][64][64]: col c=i*16+m holds (relbias+mask)*log2e for
//                    k-token sigma(i,m)=32*(i>>1)+(m>>2)*8+(i&1)*4+(m&3)
#define WS_W2T 55296
#define WS_B1P 73728
#define WS_TBL 74880

__global__ __launch_bounds__(256) void swin_prep_kernel(
    const float* __restrict__ w1, const float* __restrict__ b1,
    const float* __restrict__ w2, const float* __restrict__ relb,
    _Float16* __restrict__ w1T, _Float16* __restrict__ w2T,
    float* __restrict__ b1p, float* __restrict__ tblP)
{
    int idx = blockIdx.x * 256 + threadIdx.x;
    const float L2E = 1.4426950408889634f;
    const float qs2 = 0.17677669529663687f * L2E;   // 1/sqrt(32) * log2(e)
    if (idx < 27648) {
        int jp = idx / 96, k = idx % 96;
        float v;
        if (jp < 96) {                       // permuted Q row
            int f = jp >> 4, m = jp & 15;
            int cq = (f >> 1) * 32 + (m >> 2) * 8 + (f & 1) * 4 + (m & 3);
            v = w1[k * 288 + cq * 3] * qs2;  // orig col = cq*3 + 0 (Q interleave)
        } else {
            int jo = (jp % 96) * 3 + (jp / 96);
            v = w1[k * 288 + jo];
        }
        w1T[idx] = (_Float16)v;
    } else if (idx < 36864) {
        int i2 = idx - 27648;
        int n = i2 / 96, k = i2 % 96;
        w2T[i2] = (_Float16)w2[k * 96 + n];
    } else if (idx < 37152) {
        int jp = idx - 36864;
        float v = b1[(jp % 96) * 3 + (jp / 96)];
        if (jp < 96) v *= qs2;
        b1p[jp] = v;
    } else if (idx < 53536) {
        int t = idx - 37152;
        int vv = t >> 12, q = (t >> 6) & 63, c = t & 63;
        int i = c >> 4, m = c & 15;
        int k = (i >> 1) * 32 + (m >> 2) * 8 + (i & 1) * 4 + (m & 3);  // sigma(i,m)
        float val = -1e30f;
        if (q < 49 && k < 49) {
            val = relb[q * 49 + k] * L2E;
            if ((vv & 1) && ((q >= 28) != (k >= 28))) val = -1e30f;
            if ((vv & 2) && (((q % 7) >= 4) != ((k % 7) >= 4))) val = -1e30f;
        }
        tblP[t] = val;
    }
}

__device__ __forceinline__ unsigned int pack2h(float a, float b) {   // RTN
    union { _Float16 h[2]; unsigned int u; } p;
    p.h[0] = (_Float16)a; p.h[1] = (_Float16)b;
    return p.u;
}
__device__ __forceinline__ unsigned int pkrtz(float a, float b) {    // RTZ, 1 VALU
    return __builtin_bit_cast(unsigned int, __builtin_amdgcn_cvt_pkrtz(a, b));
}

// Block = TWO adjacent windows (b, wh, 2jw) / (b, wh, 2jw+1); 4 waves.
// Wave wv: window W = wv>>1, wsub = wv&1; owns q-rows [(wsub*2+g)*16, +16) for g=0,1
// -> two independent softmax/PV chains per wave share every kf/vf/wf fragment (2x ILP).
// P,O,Q register-resident via R6's verified fragment-permutation; bias+mask folded
// into the QK MFMA C-operand.
// LDS 54272 B (3 blocks/CU): Kb0@0, Kb1@13312 ([64][104] f16, staging aliased),
// Vt0@26624, Vt1@40448 ([96][72] f16).
__global__ __launch_bounds__(256, 3) void swin_attn_kernel(
    const float* __restrict__ x,
    const _Float16* __restrict__ w1T,
    const _Float16* __restrict__ w2T,
    const float* __restrict__ b1p,
    const float* __restrict__ b2,
    const float* __restrict__ tblP,
    float* __restrict__ out)
{
    __shared__ __align__(16) char smem[54272];

    const int tid = threadIdx.x;
    const int wv = tid >> 6, lane = tid & 63;
    const int lr = lane & 15, lg = lane >> 4;
    const int W = wv >> 1, wsub = wv & 1;

    const int gid = blockIdx.x;                  // 2048 blocks
    const int b = gid >> 5, wh = (gid >> 2) & 7, jw = gid & 3;
    const int ww = jw * 2 + W;                   // this wave's window column

    _Float16* Kb = (_Float16*)(smem + W * 13312);
    _Float16* Vt = (_Float16*)(smem + 26624 + W * 13824);
    const f32x4 fz = {0.f, 0.f, 0.f, 0.f};

    // ---- phase 0: stage both windows' rolled x -> f16 (rows 49..63 zero) ----
    {
        const int w0 = tid >> 7, p = (tid >> 1) & 63, sub = tid & 1;
        _Float16* Xw = (_Float16*)(smem + w0 * 13312);
        const int ww0 = jw * 2 + w0;
        const float* xrow = nullptr;
        if (p < 49) {
            const int m1 = p / 7, m2 = p % 7;
            int rr = wh * 7 + m1 + 4; if (rr >= 56) rr -= 56;
            int cc = ww0 * 7 + m2 + 4; if (cc >= 56) cc -= 56;
            xrow = x + ((size_t)b * 3136 + rr * 56 + cc) * 96;
        }
        #pragma unroll
        for (int j = 0; j < 12; ++j) {
            const int e = sub * 48 + j * 4;
            half4_t hv = {(_Float16)0.f, (_Float16)0.f, (_Float16)0.f, (_Float16)0.f};
            if (p < 49) {
                const float4 v = *(const float4*)(xrow + e);
                hv[0] = (_Float16)v.x; hv[1] = (_Float16)v.y;
                hv[2] = (_Float16)v.z; hv[3] = (_Float16)v.w;
            }
            *(half4_t*)(Xw + p * 104 + e) = hv;
        }
    }
    __syncthreads();

    // ---- phase 0b: all 4 row-groups' A-frags of own window -> regs ----
    half8_t xa[4][3];
    {
        const _Float16* Xs = (const _Float16*)(smem + W * 13312);
        #pragma unroll
        for (int mt = 0; mt < 4; ++mt)
            #pragma unroll
            for (int kt = 0; kt < 3; ++kt)
                xa[mt][kt] = *(const half8_t*)(Xs + (mt * 16 + lr) * 104 + kt * 32 + lg * 8);
    }
    __syncthreads();   // frags in regs before K-stores overwrite staging

    // ---- phase 1a: K,V for own window (6 nt per wave, step-2 split) ----
    #pragma unroll
    for (int t = 0; t < 6; ++t) {
        const int nt = 6 + wsub + 2 * t;
        half8_t bf[3];
        #pragma unroll
        for (int kt = 0; kt < 3; ++kt)
            bf[kt] = *(const half8_t*)(w1T + (nt * 16 + lr) * 96 + kt * 32 + lg * 8);
        const float bv = b1p[nt * 16 + lr];
        #pragma unroll
        for (int mt = 0; mt < 4; ++mt) {
            f32x4 acc = fz;
            #pragma unroll
            for (int kt = 0; kt < 3; ++kt)
                acc = __builtin_amdgcn_mfma_f32_16x16x32_f16(xa[mt][kt], bf[kt], acc, 0, 0, 0);
            if (nt < 12) {   // K: permuted rows, col^16 keyed on lg bit0
                const int kc = ((nt - 6) * 16 + lr) ^ ((lg & 1) << 4);
                #pragma unroll
                for (int r = 0; r < 4; ++r) {
                    const int krow = ((mt >> 1) * 2 + (lg & 1)) * 16
                                   + ((mt * 2 + (lg >> 1)) & 3) * 4 + r;
                    Kb[krow * 104 + kc] = (_Float16)(acc[r] + bv);
                }
            } else {         // V: e-row permuted -> PV output lands A-frag-ordered
                const int nv = nt - 12;
                const int hh = nv >> 1, eta = nv & 1;
                const int vrow = hh * 32 + ((lr >> 2) & 1) * 16
                               + (((eta << 1) + (lr >> 3)) & 3) * 4 + (lr & 3);
                half4_t hv;
                #pragma unroll
                for (int r = 0; r < 4; ++r) hv[r] = (_Float16)(acc[r] + bv);
                *(half4_t*)(Vt + vrow * 72 + mt * 16 + lg * 4) = hv;
            }
        }
    }

    // ---- phase 1b: Q as QK B-frags in regs, per row-group (permuted w1T rows) ----
    unsigned int qpk[2][3][4];
    #pragma unroll
    for (int g = 0; g < 2; ++g) {
        #pragma unroll
        for (int f = 0; f < 6; ++f) {
            f32x4 acc = fz;
            #pragma unroll
            for (int kt = 0; kt < 3; ++kt) {
                half8_t af = *(const half8_t*)(w1T + (f * 16 + lr) * 96 + kt * 32 + lg * 8);
                acc = __builtin_amdgcn_mfma_f32_16x16x32_f16(af, xa[wsub * 2 + g][kt], acc, 0, 0, 0);
            }
            const float4 bq = *(const float4*)(b1p + (f >> 1) * 32 + lg * 8 + (f & 1) * 4);
            qpk[g][f >> 1][(f & 1) * 2 + 0] = pack2h(acc[0] + bq.x, acc[1] + bq.y);
            qpk[g][f >> 1][(f & 1) * 2 + 1] = pack2h(acc[2] + bq.z, acc[3] + bq.w);
        }
    }
    __syncthreads();   // Kb/Vt visible to both waves of the window

    const float* tblv = tblP + ((wh == 7) ? 4096 : 0) + ((ww == 7) ? 8192 : 0);
    f32x4 accO[2][6];
    #pragma unroll
    for (int g = 0; g < 2; ++g)
        #pragma unroll
        for (int i = 0; i < 6; ++i) accO[g][i] = fz;

    #pragma unroll
    for (int h = 0; h < 3; ++h) {
        half8_t qv[2];
        #pragma unroll
        for (int g = 0; g < 2; ++g) {
            const u32x4 qd = {qpk[g][h][0], qpk[g][h][1], qpk[g][h][2], qpk[g][h][3]};
            qv[g] = __builtin_bit_cast(half8_t, qd);
        }
        // QK: kf shared by both groups; bias+mask via the MFMA C-operand
        f32x4 s[2][4];
        #pragma unroll
        for (int i = 0; i < 4; ++i) {
            const int col = (h * 32 + lg * 8) ^ ((i & 1) << 4);
            half8_t kf = *(const half8_t*)(Kb + (i * 16 + lr) * 104 + col);
            #pragma unroll
            for (int g = 0; g < 2; ++g) {
                const f32x4 tvv = *(const f32x4*)(tblv + ((wsub * 2 + g) * 16 + lr) * 64
                                                  + i * 16 + lg * 4);
                s[g][i] = __builtin_amdgcn_mfma_f32_16x16x32_f16(kf, qv[g], tvv, 0, 0, 0);
            }
        }
        // max-free softmax in exp2 domain; two independent chains
        float sum[2];
        half8_t pf0[2], pf1[2];
        #pragma unroll
        for (int g = 0; g < 2; ++g) {
            float sm = 0.f;
            #pragma unroll
            for (int i = 0; i < 4; ++i)
                #pragma unroll
                for (int r = 0; r < 4; ++r) {
                    const float e = exp2f(s[g][i][r]);
                    s[g][i][r] = e; sm += e;
                }
            const u32x4 p0 = {pkrtz(s[g][0][0], s[g][0][1]), pkrtz(s[g][0][2], s[g][0][3]),
                              pkrtz(s[g][1][0], s[g][1][1]), pkrtz(s[g][1][2], s[g][1][3])};
            const u32x4 p1 = {pkrtz(s[g][2][0], s[g][2][1]), pkrtz(s[g][2][2], s[g][2][3]),
                              pkrtz(s[g][3][0], s[g][3][1]), pkrtz(s[g][3][2], s[g][3][3])};
            pf0[g] = __builtin_bit_cast(half8_t, p0);
            pf1[g] = __builtin_bit_cast(half8_t, p1);
            sm += __shfl_xor(sm, 16);
            sm += __shfl_xor(sm, 32);
            sum[g] = sm;
        }
        // PV: vf shared by both groups; O lands in outproj-A-frag order
        half8_t vf00 = *(const half8_t*)(Vt + (h * 32 + lr) * 72 + lg * 8);
        half8_t vf01 = *(const half8_t*)(Vt + (h * 32 + lr) * 72 + 32 + lg * 8);
        half8_t vf10 = *(const half8_t*)(Vt + (h * 32 + 16 + lr) * 72 + lg * 8);
        half8_t vf11 = *(const half8_t*)(Vt + (h * 32 + 16 + lr) * 72 + 32 + lg * 8);
        half8_t of[2];
        #pragma unroll
        for (int g = 0; g < 2; ++g) {
            f32x4 o0 = __builtin_amdgcn_mfma_f32_16x16x32_f16(vf00, pf0[g], fz, 0, 0, 0);
            o0 = __builtin_amdgcn_mfma_f32_16x16x32_f16(vf01, pf1[g], o0, 0, 0, 0);
            f32x4 o1 = __builtin_amdgcn_mfma_f32_16x16x32_f16(vf10, pf0[g], fz, 0, 0, 0);
            o1 = __builtin_amdgcn_mfma_f32_16x16x32_f16(vf11, pf1[g], o1, 0, 0, 0);
            const float inv = 1.0f / sum[g];
            const u32x4 od = {pack2h(o0[0] * inv, o0[1] * inv), pack2h(o0[2] * inv, o0[3] * inv),
                              pack2h(o1[0] * inv, o1[1] * inv), pack2h(o1[2] * inv, o1[3] * inv)};
            of[g] = __builtin_bit_cast(half8_t, od);
        }
        // out-proj: wf shared by both groups
        #pragma unroll
        for (int nt = 0; nt < 6; ++nt) {
            half8_t wf = *(const half8_t*)(w2T + (nt * 16 + lr) * 96 + h * 32 + lg * 8);
            accO[0][nt] = __builtin_amdgcn_mfma_f32_16x16x32_f16(of[0], wf, accO[0][nt], 0, 0, 0);
            accO[1][nt] = __builtin_amdgcn_mfma_f32_16x16x32_f16(of[1], wf, accO[1][nt], 0, 0, 0);
        }
    }

    // ---- phase 3: store (+3,+3) rolled, bias; two row-groups per wave ----
    float b2v[6];
    #pragma unroll
    for (int nt = 0; nt < 6; ++nt) b2v[nt] = b2[nt * 16 + lr];
    #pragma unroll
    for (int g = 0; g < 2; ++g) {
        #pragma unroll
        for (int r = 0; r < 4; ++r) {
            const int row = (wsub * 2 + g) * 16 + lg * 4 + r;
            if (row < 49) {
                const int m1 = row / 7, m2 = row % 7;
                int oi = wh * 7 + m1 + 3; if (oi >= 56) oi -= 56;
                int oj = ww * 7 + m2 + 3; if (oj >= 56) oj -= 56;
                float* op = out + ((size_t)b * 3136 + oi * 56 + oj) * 96;
                #pragma unroll
                for (int nt = 0; nt < 6; ++nt)
                    op[nt * 16 + lr] = accO[g][nt][r] + b2v[nt];
            }
        }
    }
}

extern "C" void kernel_launch(void* const* d_in, const int* in_sizes, int n_in,
                              void* d_out, int out_size, void* d_ws, size_t ws_size,
                              hipStream_t stream) {
    const float* x    = (const float*)d_in[0];
    const float* w1   = (const float*)d_in[1];
    const float* b1   = (const float*)d_in[2];
    const float* w2   = (const float*)d_in[3];
    const float* b2   = (const float*)d_in[4];
    const float* relb = (const float*)d_in[5];
    float* out = (float*)d_out;

    _Float16* w1T  = (_Float16*)((char*)d_ws);
    _Float16* w2T  = (_Float16*)((char*)d_ws + WS_W2T);
    float*    b1p  = (float*)((char*)d_ws + WS_B1P);
    float*    tblP = (float*)((char*)d_ws + WS_TBL);

    swin_prep_kernel<<<210, 256, 0, stream>>>(w1, b1, w2, relb, w1T, w2T, b1p, tblP);
    swin_attn_kernel<<<2048, 256, 0, stream>>>(x, w1T, w2T, b1p, b2, tblP, out);
}

// Round 8
// 91.434 us; speedup vs baseline: 1.1526x; 1.1526x over previous
//
#include <hip/hip_runtime.h>
#include <hip/hip_fp16.h>

typedef _Float16 half8_t __attribute__((ext_vector_type(8)));
typedef _Float16 half4_t __attribute__((ext_vector_type(4)));
typedef float f32x4 __attribute__((ext_vector_type(4)));
typedef unsigned int u32x4 __attribute__((ext_vector_type(4)));

// ws: [0,55296)      w1T fp16 [288][96]; rows 0..95 = Q cols PERMUTED (row f*16+m ->
//                    Q col (f>>1)*32+(m>>2)*8+(f&1)*4+(m&3)), scaled by qs*log2e;
//                    rows 96..287 = K,V cols (plain order, unscaled)
//     [55296,73728)  w2T fp16 [96][96]
//     [73728,74880)  b1p f32 [288] (orig col order; Q entries scaled by qs*log2e)
//     [74880,140416) tblP f32 [4][64][64]: col c=i*16+m holds (relbias+mask)*log2e for
//                    k-token sigma(i,m)=32*(i>>1)+(m>>2)*8+(i&1)*4+(m&3)
#define WS_W2T 55296
#define WS_B1P 73728
#define WS_TBL 74880

__global__ __launch_bounds__(256) void swin_prep_kernel(
    const float* __restrict__ w1, const float* __restrict__ b1,
    const float* __restrict__ w2, const float* __restrict__ relb,
    _Float16* __restrict__ w1T, _Float16* __restrict__ w2T,
    float* __restrict__ b1p, float* __restrict__ tblP)
{
    int idx = blockIdx.x * 256 + threadIdx.x;
    const float L2E = 1.4426950408889634f;
    const float qs2 = 0.17677669529663687f * L2E;   // 1/sqrt(32) * log2(e)
    if (idx < 27648) {
        int jp = idx / 96, k = idx % 96;
        float v;
        if (jp < 96) {                       // permuted Q row
            int f = jp >> 4, m = jp & 15;
            int cq = (f >> 1) * 32 + (m >> 2) * 8 + (f & 1) * 4 + (m & 3);
            v = w1[k * 288 + cq * 3] * qs2;  // orig col = cq*3 + 0 (Q interleave)
        } else {
            int jo = (jp % 96) * 3 + (jp / 96);
            v = w1[k * 288 + jo];
        }
        w1T[idx] = (_Float16)v;
    } else if (idx < 36864) {
        int i2 = idx - 27648;
        int n = i2 / 96, k = i2 % 96;
        w2T[i2] = (_Float16)w2[k * 96 + n];
    } else if (idx < 37152) {
        int jp = idx - 36864;
        float v = b1[(jp % 96) * 3 + (jp / 96)];
        if (jp < 96) v *= qs2;
        b1p[jp] = v;
    } else if (idx < 53536) {
        int t = idx - 37152;
        int vv = t >> 12, q = (t >> 6) & 63, c = t & 63;
        int i = c >> 4, m = c & 15;
        int k = (i >> 1) * 32 + (m >> 2) * 8 + (i & 1) * 4 + (m & 3);  // sigma(i,m)
        float val = -1e30f;
        if (q < 49 && k < 49) {
            val = relb[q * 49 + k] * L2E;
            if ((vv & 1) && ((q >= 28) != (k >= 28))) val = -1e30f;
            if ((vv & 2) && (((q % 7) >= 4) != ((k % 7) >= 4))) val = -1e30f;
        }
        tblP[t] = val;
    }
}

__device__ __forceinline__ unsigned int pack2h(float a, float b) {   // RTN
    union { _Float16 h[2]; unsigned int u; } p;
    p.h[0] = (_Float16)a; p.h[1] = (_Float16)b;
    return p.u;
}
__device__ __forceinline__ unsigned int pkrtz(float a, float b) {    // RTZ, 1 VALU
    return __builtin_bit_cast(unsigned int, __builtin_amdgcn_cvt_pkrtz(a, b));
}

// One block = one (batch, wrow, wcol) window; 4 waves; wave owns q-rows [wv*16,+16).
// R6's verified fragment-permutation algebra (P,O,Q register-resident) +
// R5's load-pipelining discipline (weight prefetch; wf/vf hoisted under softmax) +
// bias/mask folded into the QK MFMA C-operand.
// LDS (27136 B, 4+ blocks/CU): Kb [64][104] f16 @0 (aliases phase-0 staging);
// Vt [96][72] f16 @13312.
__global__ __launch_bounds__(256, 4) void swin_attn_kernel(
    const float* __restrict__ x,
    const _Float16* __restrict__ w1T,
    const _Float16* __restrict__ w2T,
    const float* __restrict__ b1p,
    const float* __restrict__ b2,
    const float* __restrict__ tblP,
    float* __restrict__ out)
{
    __shared__ __align__(16) char smem[27136];
    _Float16* Kb = (_Float16*)smem;            // [64][104]
    _Float16* Vt = (_Float16*)(smem + 13312);  // [96][72]
    _Float16* Xs = Kb;                         // phase-0 x staging (aliased)

    const int tid = threadIdx.x;
    const int wv = tid >> 6, lane = tid & 63;
    const int lr = lane & 15, lg = lane >> 4;

    const int gid = blockIdx.x;
    const int b = gid >> 6, wh = (gid >> 3) & 7, ww = gid & 7;
    const f32x4 fz = {0.f, 0.f, 0.f, 0.f};

    // ---- phase 0: stage rolled x window -> Xs fp16 (rows 49..63 zeroed) ----
    {
        const int p = tid >> 2, sub = tid & 3;
        const float* xrow = nullptr;
        if (p < 49) {
            const int m1 = p / 7, m2 = p % 7;
            int rr = wh * 7 + m1 + 4; if (rr >= 56) rr -= 56;
            int cc = ww * 7 + m2 + 4; if (cc >= 56) cc -= 56;
            xrow = x + ((size_t)b * 3136 + rr * 56 + cc) * 96;
        }
        #pragma unroll
        for (int j = 0; j < 6; ++j) {
            const int e = sub * 24 + j * 4;
            half4_t hv = {(_Float16)0.f, (_Float16)0.f, (_Float16)0.f, (_Float16)0.f};
            if (p < 49) {
                const float4 v = *(const float4*)(xrow + e);
                hv[0] = (_Float16)v.x; hv[1] = (_Float16)v.y;
                hv[2] = (_Float16)v.z; hv[3] = (_Float16)v.w;
            }
            *(half4_t*)(Xs + p * 104 + e) = hv;
        }
    }
    __syncthreads();

    // ---- phase 0b: A-frags for all 4 row-groups + own-row copy -> regs ----
    half8_t xa[4][3], xq[3];
    #pragma unroll
    for (int mt = 0; mt < 4; ++mt)
        #pragma unroll
        for (int kt = 0; kt < 3; ++kt)
            xa[mt][kt] = *(const half8_t*)(Xs + (mt * 16 + lr) * 104 + kt * 32 + lg * 8);
    #pragma unroll
    for (int kt = 0; kt < 3; ++kt)
        xq[kt] = *(const half8_t*)(Xs + (wv * 16 + lr) * 104 + kt * 32 + lg * 8);
    __syncthreads();   // xa/xq reads complete before K overwrites the staging region

    // ---- phase 1a: K,V (nt-split across waves; permuted stores; prefetched) ----
    {
        half8_t bf0, bf1, bf2; float bv;
        {
            const int nt0 = 6 + wv;
            bf0 = *(const half8_t*)(w1T + (nt0 * 16 + lr) * 96 + lg * 8);
            bf1 = *(const half8_t*)(w1T + (nt0 * 16 + lr) * 96 + 32 + lg * 8);
            bf2 = *(const half8_t*)(w1T + (nt0 * 16 + lr) * 96 + 64 + lg * 8);
            bv = b1p[nt0 * 16 + lr];
        }
        #pragma unroll
        for (int t = 0; t < 3; ++t) {
            const int nt = 6 + wv + 4 * t;     // 6..17
            half8_t nf0 = bf0, nf1 = bf1, nf2 = bf2; float nbv = bv;
            if (t < 2) {   // prefetch next iteration's weights
                const int ntn = nt + 4;
                nf0 = *(const half8_t*)(w1T + (ntn * 16 + lr) * 96 + lg * 8);
                nf1 = *(const half8_t*)(w1T + (ntn * 16 + lr) * 96 + 32 + lg * 8);
                nf2 = *(const half8_t*)(w1T + (ntn * 16 + lr) * 96 + 64 + lg * 8);
                nbv = b1p[ntn * 16 + lr];
            }
            #pragma unroll
            for (int mt = 0; mt < 4; ++mt) {
                f32x4 acc = fz;
                acc = __builtin_amdgcn_mfma_f32_16x16x32_f16(xa[mt][0], bf0, acc, 0, 0, 0);
                acc = __builtin_amdgcn_mfma_f32_16x16x32_f16(xa[mt][1], bf1, acc, 0, 0, 0);
                acc = __builtin_amdgcn_mfma_f32_16x16x32_f16(xa[mt][2], bf2, acc, 0, 0, 0);
                if (nt < 12) {   // K: permuted rows, col^16 keyed on lg bit0
                    const int kc = ((nt - 6) * 16 + lr) ^ ((lg & 1) << 4);
                    #pragma unroll
                    for (int r = 0; r < 4; ++r) {
                        const int krow = ((mt >> 1) * 2 + (lg & 1)) * 16
                                       + ((mt * 2 + (lg >> 1)) & 3) * 4 + r;
                        Kb[krow * 104 + kc] = (_Float16)(acc[r] + bv);
                    }
                } else {         // V: e-row permuted -> PV output lands A-frag-ordered
                    const int nv = nt - 12;
                    const int hh = nv >> 1, eta = nv & 1;
                    const int vrow = hh * 32 + ((lr >> 2) & 1) * 16
                                   + (((eta << 1) + (lr >> 3)) & 3) * 4 + (lr & 3);
                    half4_t hv;
                    #pragma unroll
                    for (int r = 0; r < 4; ++r) hv[r] = (_Float16)(acc[r] + bv);
                    *(half4_t*)(Vt + vrow * 72 + mt * 16 + lg * 4) = hv;
                }
            }
            bf0 = nf0; bf1 = nf1; bf2 = nf2; bv = nbv;
        }
    }

    // ---- phase 1b: Q as QK B-frags in regs (permuted w1T rows; prefetched) ----
    unsigned int qpk[3][4];
    {
        half8_t af0 = *(const half8_t*)(w1T + lr * 96 + lg * 8);
        half8_t af1 = *(const half8_t*)(w1T + lr * 96 + 32 + lg * 8);
        half8_t af2 = *(const half8_t*)(w1T + lr * 96 + 64 + lg * 8);
        #pragma unroll
        for (int f = 0; f < 6; ++f) {          // h = f>>1, jj = f&1
            half8_t n0 = af0, n1 = af1, n2 = af2;
            if (f < 5) {
                n0 = *(const half8_t*)(w1T + ((f + 1) * 16 + lr) * 96 + lg * 8);
                n1 = *(const half8_t*)(w1T + ((f + 1) * 16 + lr) * 96 + 32 + lg * 8);
                n2 = *(const half8_t*)(w1T + ((f + 1) * 16 + lr) * 96 + 64 + lg * 8);
            }
            f32x4 acc = fz;
            acc = __builtin_amdgcn_mfma_f32_16x16x32_f16(af0, xq[0], acc, 0, 0, 0);
            acc = __builtin_amdgcn_mfma_f32_16x16x32_f16(af1, xq[1], acc, 0, 0, 0);
            acc = __builtin_amdgcn_mfma_f32_16x16x32_f16(af2, xq[2], acc, 0, 0, 0);
            const float4 bq = *(const float4*)(b1p + (f >> 1) * 32 + lg * 8 + (f & 1) * 4);
            qpk[f >> 1][(f & 1) * 2 + 0] = pack2h(acc[0] + bq.x, acc[1] + bq.y);
            qpk[f >> 1][(f & 1) * 2 + 1] = pack2h(acc[2] + bq.z, acc[3] + bq.w);
            af0 = n0; af1 = n1; af2 = n2;
        }
    }

    // bias/mask table rows (permuted to match sigma) -> regs; loaded here so they
    // are not live during phase 1 (register peak) and hide under the barrier wait
    f32x4 tv[4];
    {
        const float* tblv = tblP + ((wh == 7) ? 4096 : 0) + ((ww == 7) ? 8192 : 0)
                          + (wv * 16 + lr) * 64 + lg * 4;
        #pragma unroll
        for (int i = 0; i < 4; ++i)
            tv[i] = *(const f32x4*)(tblv + i * 16);
    }
    __syncthreads();   // Kb/Vt visible to all waves

    f32x4 accO[6];
    #pragma unroll
    for (int i = 0; i < 6; ++i) accO[i] = fz;

    #pragma unroll
    for (int h = 0; h < 3; ++h) {
        const u32x4 qd = {qpk[h][0], qpk[h][1], qpk[h][2], qpk[h][3]};
        const half8_t qv = __builtin_bit_cast(half8_t, qd);

        // QK: mfma i holds S[token sigma(i,·)][q=wv*16+lr]; bias+mask via C-operand
        f32x4 s[4];
        #pragma unroll
        for (int i = 0; i < 4; ++i) {
            const int col = (h * 32 + lg * 8) ^ ((i & 1) << 4);
            half8_t kf = *(const half8_t*)(Kb + (i * 16 + lr) * 104 + col);
            s[i] = __builtin_amdgcn_mfma_f32_16x16x32_f16(kf, qv, tv[i], 0, 0, 0);
        }
        // issue V + w2T loads now; latency hides under softmax VALU
        half8_t vf00 = *(const half8_t*)(Vt + (h * 32 + lr) * 72 + lg * 8);
        half8_t vf01 = *(const half8_t*)(Vt + (h * 32 + lr) * 72 + 32 + lg * 8);
        half8_t vf10 = *(const half8_t*)(Vt + (h * 32 + 16 + lr) * 72 + lg * 8);
        half8_t vf11 = *(const half8_t*)(Vt + (h * 32 + 16 + lr) * 72 + 32 + lg * 8);
        half8_t wf[6];
        #pragma unroll
        for (int nt = 0; nt < 6; ++nt)
            wf[nt] = *(const half8_t*)(w2T + (nt * 16 + lr) * 96 + h * 32 + lg * 8);

        // max-free softmax in exp2 domain; 4 independent partial-sum chains
        float ps[4];
        #pragma unroll
        for (int i = 0; i < 4; ++i) {
            float a0 = exp2f(s[i][0]), a1 = exp2f(s[i][1]);
            float a2 = exp2f(s[i][2]), a3 = exp2f(s[i][3]);
            s[i][0] = a0; s[i][1] = a1; s[i][2] = a2; s[i][3] = a3;
            ps[i] = (a0 + a1) + (a2 + a3);
        }
        float sum = (ps[0] + ps[1]) + (ps[2] + ps[3]);
        const u32x4 p0 = {pkrtz(s[0][0], s[0][1]), pkrtz(s[0][2], s[0][3]),
                          pkrtz(s[1][0], s[1][1]), pkrtz(s[1][2], s[1][3])};
        const u32x4 p1 = {pkrtz(s[2][0], s[2][1]), pkrtz(s[2][2], s[2][3]),
                          pkrtz(s[3][0], s[3][1]), pkrtz(s[3][2], s[3][3])};
        const half8_t pf0 = __builtin_bit_cast(half8_t, p0);
        const half8_t pf1 = __builtin_bit_cast(half8_t, p1);
        sum += __shfl_xor(sum, 16);
        sum += __shfl_xor(sum, 32);
        // PV: O lands in outproj-A-frag order (el = lg*8 + jj*4 + r)
        f32x4 o0 = __builtin_amdgcn_mfma_f32_16x16x32_f16(vf00, pf0, fz, 0, 0, 0);
        o0 = __builtin_amdgcn_mfma_f32_16x16x32_f16(vf01, pf1, o0, 0, 0, 0);
        f32x4 o1 = __builtin_amdgcn_mfma_f32_16x16x32_f16(vf10, pf0, fz, 0, 0, 0);
        o1 = __builtin_amdgcn_mfma_f32_16x16x32_f16(vf11, pf1, o1, 0, 0, 0);
        const float inv = 1.0f / sum;   // normalize O once (cheaper than P)
        const u32x4 od = {pkrtz(o0[0] * inv, o0[1] * inv), pkrtz(o0[2] * inv, o0[3] * inv),
                          pkrtz(o1[0] * inv, o1[1] * inv), pkrtz(o1[2] * inv, o1[3] * inv)};
        const half8_t of = __builtin_bit_cast(half8_t, od);
        // out-proj slice
        #pragma unroll
        for (int nt = 0; nt < 6; ++nt)
            accO[nt] = __builtin_amdgcn_mfma_f32_16x16x32_f16(of, wf[nt], accO[nt], 0, 0, 0);
    }

    // ---- phase 3: store (+3,+3) rolled, bias ----
    float b2v[6];
    #pragma unroll
    for (int nt = 0; nt < 6; ++nt) b2v[nt] = b2[nt * 16 + lr];
    #pragma unroll
    for (int r = 0; r < 4; ++r) {
        const int row = wv * 16 + lg * 4 + r;
        if (row < 49) {
            const int m1 = row / 7, m2 = row % 7;
            int oi = wh * 7 + m1 + 3; if (oi >= 56) oi -= 56;
            int oj = ww * 7 + m2 + 3; if (oj >= 56) oj -= 56;
            float* op = out + ((size_t)b * 3136 + oi * 56 + oj) * 96;
            #pragma unroll
            for (int nt = 0; nt < 6; ++nt)
                op[nt * 16 + lr] = accO[nt][r] + b2v[nt];
        }
    }
}

extern "C" void kernel_launch(void* const* d_in, const int* in_sizes, int n_in,
                              void* d_out, int out_size, void* d_ws, size_t ws_size,
                              hipStream_t stream) {
    const float* x    = (const float*)d_in[0];
    const float* w1   = (const float*)d_in[1];
    const float* b1   = (const float*)d_in[2];
    const float* w2   = (const float*)d_in[3];
    const float* b2   = (const float*)d_in[4];
    const float* relb = (const float*)d_in[5];
    float* out = (float*)d_out;

    _Float16* w1T  = (_Float16*)((char*)d_ws);
    _Float16* w2T  = (_Float16*)((char*)d_ws + WS_W2T);
    float*    b1p  = (float*)((char*)d_ws + WS_B1P);
    float*    tblP = (float*)((char*)d_ws + WS_TBL);

    swin_prep_kernel<<<210, 256, 0, stream>>>(w1, b1, w2, relb, w1T, w2T, b1p, tblP);
    swin_attn_kernel<<<4096, 256, 0, stream>>>(x, w1T, w2T, b1p, b2, tblP, out);
}

// Round 9
// 83.292 us; speedup vs baseline: 1.2652x; 1.0977x over previous
//
#include <hip/hip_runtime.h>
#include <hip/hip_fp16.h>

typedef _Float16 half8_t __attribute__((ext_vector_type(8)));
typedef _Float16 half4_t __attribute__((ext_vector_type(4)));
typedef float f32x4 __attribute__((ext_vector_type(4)));
typedef unsigned int u32x4 __attribute__((ext_vector_type(4)));

// ws: [0,55296)      w1T fp16 [288][96]; rows 0..95 = Q cols PERMUTED (row f*16+m ->
//                    Q col (f>>1)*32+(m>>2)*8+(f&1)*4+(m&3)), scaled by qs*log2e;
//                    rows 96..287 = K,V cols (plain order, unscaled)
//     [55296,73728)  w2T fp16 [96][96]
//     [73728,74880)  b1p f32 [288] (orig col order; Q entries scaled by qs*log2e)
//     [74880,140416) tblP f32 [4][64][64]: col c=i*16+m holds (relbias+mask)*log2e for
//                    k-token sigma(i,m)=32*(i>>1)+(m>>2)*8+(i&1)*4+(m&3)
#define WS_W2T 55296
#define WS_B1P 73728
#define WS_TBL 74880

__global__ __launch_bounds__(256) void swin_prep_kernel(
    const float* __restrict__ w1, const float* __restrict__ b1,
    const float* __restrict__ w2, const float* __restrict__ relb,
    _Float16* __restrict__ w1T, _Float16* __restrict__ w2T,
    float* __restrict__ b1p, float* __restrict__ tblP)
{
    int idx = blockIdx.x * 256 + threadIdx.x;
    const float L2E = 1.4426950408889634f;
    const float qs2 = 0.17677669529663687f * L2E;   // 1/sqrt(32) * log2(e)
    if (idx < 27648) {
        int jp = idx / 96, k = idx % 96;
        float v;
        if (jp < 96) {                       // permuted Q row
            int f = jp >> 4, m = jp & 15;
            int cq = (f >> 1) * 32 + (m >> 2) * 8 + (f & 1) * 4 + (m & 3);
            v = w1[k * 288 + cq * 3] * qs2;  // orig col = cq*3 + 0 (Q interleave)
        } else {
            int jo = (jp % 96) * 3 + (jp / 96);
            v = w1[k * 288 + jo];
        }
        w1T[idx] = (_Float16)v;
    } else if (idx < 36864) {
        int i2 = idx - 27648;
        int n = i2 / 96, k = i2 % 96;
        w2T[i2] = (_Float16)w2[k * 96 + n];
    } else if (idx < 37152) {
        int jp = idx - 36864;
        float v = b1[(jp % 96) * 3 + (jp / 96)];
        if (jp < 96) v *= qs2;
        b1p[jp] = v;
    } else if (idx < 53536) {
        int t = idx - 37152;
        int vv = t >> 12, q = (t >> 6) & 63, c = t & 63;
        int i = c >> 4, m = c & 15;
        int k = (i >> 1) * 32 + (m >> 2) * 8 + (i & 1) * 4 + (m & 3);  // sigma(i,m)
        float val = -1e30f;
        if (q < 49 && k < 49) {
            val = relb[q * 49 + k] * L2E;
            if ((vv & 1) && ((q >= 28) != (k >= 28))) val = -1e30f;
            if ((vv & 2) && (((q % 7) >= 4) != ((k % 7) >= 4))) val = -1e30f;
        }
        tblP[t] = val;
    }
}

__device__ __forceinline__ unsigned int pack2h(float a, float b) {   // RTN
    union { _Float16 h[2]; unsigned int u; } p;
    p.h[0] = (_Float16)a; p.h[1] = (_Float16)b;
    return p.u;
}
__device__ __forceinline__ unsigned int pkrtz(float a, float b) {    // RTZ, 1 VALU
    return __builtin_bit_cast(unsigned int, __builtin_amdgcn_cvt_pkrtz(a, b));
}

// One block = one (batch, wrow, wcol) window; 4 waves; wave owns q-rows [wv*16,+16).
// Identical to R8 except __launch_bounds__(256) with NO min-waves arg: the (256,4)
// variant made the allocator cap VGPRs at 64 and spill ~11KB/block to scratch
// (WRITE_SIZE 75->121MB signature). LDS 27136 B.
__global__ __launch_bounds__(256) void swin_attn_kernel(
    const float* __restrict__ x,
    const _Float16* __restrict__ w1T,
    const _Float16* __restrict__ w2T,
    const float* __restrict__ b1p,
    const float* __restrict__ b2,
    const float* __restrict__ tblP,
    float* __restrict__ out)
{
    __shared__ __align__(16) char smem[27136];
    _Float16* Kb = (_Float16*)smem;            // [64][104]
    _Float16* Vt = (_Float16*)(smem + 13312);  // [96][72]
    _Float16* Xs = Kb;                         // phase-0 x staging (aliased)

    const int tid = threadIdx.x;
    const int wv = tid >> 6, lane = tid & 63;
    const int lr = lane & 15, lg = lane >> 4;

    const int gid = blockIdx.x;
    const int b = gid >> 6, wh = (gid >> 3) & 7, ww = gid & 7;
    const f32x4 fz = {0.f, 0.f, 0.f, 0.f};

    // ---- phase 0: stage rolled x window -> Xs fp16 (rows 49..63 zeroed) ----
    {
        const int p = tid >> 2, sub = tid & 3;
        const float* xrow = nullptr;
        if (p < 49) {
            const int m1 = p / 7, m2 = p % 7;
            int rr = wh * 7 + m1 + 4; if (rr >= 56) rr -= 56;
            int cc = ww * 7 + m2 + 4; if (cc >= 56) cc -= 56;
            xrow = x + ((size_t)b * 3136 + rr * 56 + cc) * 96;
        }
        #pragma unroll
        for (int j = 0; j < 6; ++j) {
            const int e = sub * 24 + j * 4;
            half4_t hv = {(_Float16)0.f, (_Float16)0.f, (_Float16)0.f, (_Float16)0.f};
            if (p < 49) {
                const float4 v = *(const float4*)(xrow + e);
                hv[0] = (_Float16)v.x; hv[1] = (_Float16)v.y;
                hv[2] = (_Float16)v.z; hv[3] = (_Float16)v.w;
            }
            *(half4_t*)(Xs + p * 104 + e) = hv;
        }
    }
    __syncthreads();

    // ---- phase 0b: A-frags for all 4 row-groups + own-row copy -> regs ----
    half8_t xa[4][3], xq[3];
    #pragma unroll
    for (int mt = 0; mt < 4; ++mt)
        #pragma unroll
        for (int kt = 0; kt < 3; ++kt)
            xa[mt][kt] = *(const half8_t*)(Xs + (mt * 16 + lr) * 104 + kt * 32 + lg * 8);
    #pragma unroll
    for (int kt = 0; kt < 3; ++kt)
        xq[kt] = *(const half8_t*)(Xs + (wv * 16 + lr) * 104 + kt * 32 + lg * 8);
    __syncthreads();   // xa/xq reads complete before K overwrites the staging region

    // ---- phase 1a: K,V (nt-split across waves; permuted stores; prefetched) ----
    {
        half8_t bf0, bf1, bf2; float bv;
        {
            const int nt0 = 6 + wv;
            bf0 = *(const half8_t*)(w1T + (nt0 * 16 + lr) * 96 + lg * 8);
            bf1 = *(const half8_t*)(w1T + (nt0 * 16 + lr) * 96 + 32 + lg * 8);
            bf2 = *(const half8_t*)(w1T + (nt0 * 16 + lr) * 96 + 64 + lg * 8);
            bv = b1p[nt0 * 16 + lr];
        }
        #pragma unroll
        for (int t = 0; t < 3; ++t) {
            const int nt = 6 + wv + 4 * t;     // 6..17
            half8_t nf0 = bf0, nf1 = bf1, nf2 = bf2; float nbv = bv;
            if (t < 2) {   // prefetch next iteration's weights
                const int ntn = nt + 4;
                nf0 = *(const half8_t*)(w1T + (ntn * 16 + lr) * 96 + lg * 8);
                nf1 = *(const half8_t*)(w1T + (ntn * 16 + lr) * 96 + 32 + lg * 8);
                nf2 = *(const half8_t*)(w1T + (ntn * 16 + lr) * 96 + 64 + lg * 8);
                nbv = b1p[ntn * 16 + lr];
            }
            #pragma unroll
            for (int mt = 0; mt < 4; ++mt) {
                f32x4 acc = fz;
                acc = __builtin_amdgcn_mfma_f32_16x16x32_f16(xa[mt][0], bf0, acc, 0, 0, 0);
                acc = __builtin_amdgcn_mfma_f32_16x16x32_f16(xa[mt][1], bf1, acc, 0, 0, 0);
                acc = __builtin_amdgcn_mfma_f32_16x16x32_f16(xa[mt][2], bf2, acc, 0, 0, 0);
                if (nt < 12) {   // K: permuted rows, col^16 keyed on lg bit0
                    const int kc = ((nt - 6) * 16 + lr) ^ ((lg & 1) << 4);
                    #pragma unroll
                    for (int r = 0; r < 4; ++r) {
                        const int krow = ((mt >> 1) * 2 + (lg & 1)) * 16
                                       + ((mt * 2 + (lg >> 1)) & 3) * 4 + r;
                        Kb[krow * 104 + kc] = (_Float16)(acc[r] + bv);
                    }
                } else {         // V: e-row permuted -> PV output lands A-frag-ordered
                    const int nv = nt - 12;
                    const int hh = nv >> 1, eta = nv & 1;
                    const int vrow = hh * 32 + ((lr >> 2) & 1) * 16
                                   + (((eta << 1) + (lr >> 3)) & 3) * 4 + (lr & 3);
                    half4_t hv;
                    #pragma unroll
                    for (int r = 0; r < 4; ++r) hv[r] = (_Float16)(acc[r] + bv);
                    *(half4_t*)(Vt + vrow * 72 + mt * 16 + lg * 4) = hv;
                }
            }
            bf0 = nf0; bf1 = nf1; bf2 = nf2; bv = nbv;
        }
    }

    // ---- phase 1b: Q as QK B-frags in regs (permuted w1T rows; prefetched) ----
    unsigned int qpk[3][4];
    {
        half8_t af0 = *(const half8_t*)(w1T + lr * 96 + lg * 8);
        half8_t af1 = *(const half8_t*)(w1T + lr * 96 + 32 + lg * 8);
        half8_t af2 = *(const half8_t*)(w1T + lr * 96 + 64 + lg * 8);
        #pragma unroll
        for (int f = 0; f < 6; ++f) {          // h = f>>1, jj = f&1
            half8_t n0 = af0, n1 = af1, n2 = af2;
            if (f < 5) {
                n0 = *(const half8_t*)(w1T + ((f + 1) * 16 + lr) * 96 + lg * 8);
                n1 = *(const half8_t*)(w1T + ((f + 1) * 16 + lr) * 96 + 32 + lg * 8);
                n2 = *(const half8_t*)(w1T + ((f + 1) * 16 + lr) * 96 + 64 + lg * 8);
            }
            f32x4 acc = fz;
            acc = __builtin_amdgcn_mfma_f32_16x16x32_f16(af0, xq[0], acc, 0, 0, 0);
            acc = __builtin_amdgcn_mfma_f32_16x16x32_f16(af1, xq[1], acc, 0, 0, 0);
            acc = __builtin_amdgcn_mfma_f32_16x16x32_f16(af2, xq[2], acc, 0, 0, 0);
            const float4 bq = *(const float4*)(b1p + (f >> 1) * 32 + lg * 8 + (f & 1) * 4);
            qpk[f >> 1][(f & 1) * 2 + 0] = pack2h(acc[0] + bq.x, acc[1] + bq.y);
            qpk[f >> 1][(f & 1) * 2 + 1] = pack2h(acc[2] + bq.z, acc[3] + bq.w);
            af0 = n0; af1 = n1; af2 = n2;
        }
    }

    // bias/mask table rows (permuted to match sigma) -> regs
    f32x4 tv[4];
    {
        const float* tblv = tblP + ((wh == 7) ? 4096 : 0) + ((ww == 7) ? 8192 : 0)
                          + (wv * 16 + lr) * 64 + lg * 4;
        #pragma unroll
        for (int i = 0; i < 4; ++i)
            tv[i] = *(const f32x4*)(tblv + i * 16);
    }
    __syncthreads();   // Kb/Vt visible to all waves

    f32x4 accO[6];
    #pragma unroll
    for (int i = 0; i < 6; ++i) accO[i] = fz;

    #pragma unroll
    for (int h = 0; h < 3; ++h) {
        const u32x4 qd = {qpk[h][0], qpk[h][1], qpk[h][2], qpk[h][3]};
        const half8_t qv = __builtin_bit_cast(half8_t, qd);

        // QK: mfma i holds S[token sigma(i,·)][q=wv*16+lr]; bias+mask via C-operand
        f32x4 s[4];
        #pragma unroll
        for (int i = 0; i < 4; ++i) {
            const int col = (h * 32 + lg * 8) ^ ((i & 1) << 4);
            half8_t kf = *(const half8_t*)(Kb + (i * 16 + lr) * 104 + col);
            s[i] = __builtin_amdgcn_mfma_f32_16x16x32_f16(kf, qv, tv[i], 0, 0, 0);
        }
        // issue V + w2T loads now; latency hides under softmax VALU
        half8_t vf00 = *(const half8_t*)(Vt + (h * 32 + lr) * 72 + lg * 8);
        half8_t vf01 = *(const half8_t*)(Vt + (h * 32 + lr) * 72 + 32 + lg * 8);
        half8_t vf10 = *(const half8_t*)(Vt + (h * 32 + 16 + lr) * 72 + lg * 8);
        half8_t vf11 = *(const half8_t*)(Vt + (h * 32 + 16 + lr) * 72 + 32 + lg * 8);
        half8_t wf[6];
        #pragma unroll
        for (int nt = 0; nt < 6; ++nt)
            wf[nt] = *(const half8_t*)(w2T + (nt * 16 + lr) * 96 + h * 32 + lg * 8);

        // max-free softmax in exp2 domain; 4 independent partial-sum chains
        float ps[4];
        #pragma unroll
        for (int i = 0; i < 4; ++i) {
            float a0 = exp2f(s[i][0]), a1 = exp2f(s[i][1]);
            float a2 = exp2f(s[i][2]), a3 = exp2f(s[i][3]);
            s[i][0] = a0; s[i][1] = a1; s[i][2] = a2; s[i][3] = a3;
            ps[i] = (a0 + a1) + (a2 + a3);
        }
        float sum = (ps[0] + ps[1]) + (ps[2] + ps[3]);
        const u32x4 p0 = {pkrtz(s[0][0], s[0][1]), pkrtz(s[0][2], s[0][3]),
                          pkrtz(s[1][0], s[1][1]), pkrtz(s[1][2], s[1][3])};
        const u32x4 p1 = {pkrtz(s[2][0], s[2][1]), pkrtz(s[2][2], s[2][3]),
                          pkrtz(s[3][0], s[3][1]), pkrtz(s[3][2], s[3][3])};
        const half8_t pf0 = __builtin_bit_cast(half8_t, p0);
        const half8_t pf1 = __builtin_bit_cast(half8_t, p1);
        sum += __shfl_xor(sum, 16);
        sum += __shfl_xor(sum, 32);
        // PV: O lands in outproj-A-frag order (el = lg*8 + jj*4 + r)
        f32x4 o0 = __builtin_amdgcn_mfma_f32_16x16x32_f16(vf00, pf0, fz, 0, 0, 0);
        o0 = __builtin_amdgcn_mfma_f32_16x16x32_f16(vf01, pf1, o0, 0, 0, 0);
        f32x4 o1 = __builtin_amdgcn_mfma_f32_16x16x32_f16(vf10, pf0, fz, 0, 0, 0);
        o1 = __builtin_amdgcn_mfma_f32_16x16x32_f16(vf11, pf1, o1, 0, 0, 0);
        const float inv = 1.0f / sum;   // normalize O once (cheaper than P)
        const u32x4 od = {pkrtz(o0[0] * inv, o0[1] * inv), pkrtz(o0[2] * inv, o0[3] * inv),
                          pkrtz(o1[0] * inv, o1[1] * inv), pkrtz(o1[2] * inv, o1[3] * inv)};
        const half8_t of = __builtin_bit_cast(half8_t, od);
        // out-proj slice
        #pragma unroll
        for (int nt = 0; nt < 6; ++nt)
            accO[nt] = __builtin_amdgcn_mfma_f32_16x16x32_f16(of, wf[nt], accO[nt], 0, 0, 0);
    }

    // ---- phase 3: store (+3,+3) rolled, bias ----
    float b2v[6];
    #pragma unroll
    for (int nt = 0; nt < 6; ++nt) b2v[nt] = b2[nt * 16 + lr];
    #pragma unroll
    for (int r = 0; r < 4; ++r) {
        const int row = wv * 16 + lg * 4 + r;
        if (row < 49) {
            const int m1 = row / 7, m2 = row % 7;
            int oi = wh * 7 + m1 + 3; if (oi >= 56) oi -= 56;
            int oj = ww * 7 + m2 + 3; if (oj >= 56) oj -= 56;
            float* op = out + ((size_t)b * 3136 + oi * 56 + oj) * 96;
            #pragma unroll
            for (int nt = 0; nt < 6; ++nt)
                op[nt * 16 + lr] = accO[nt][r] + b2v[nt];
        }
    }
}

extern "C" void kernel_launch(void* const* d_in, const int* in_sizes, int n_in,
                              void* d_out, int out_size, void* d_ws, size_t ws_size,
                              hipStream_t stream) {
    const float* x    = (const float*)d_in[0];
    const float* w1   = (const float*)d_in[1];
    const float* b1   = (const float*)d_in[2];
    const float* w2   = (const float*)d_in[3];
    const float* b2   = (const float*)d_in[4];
    const float* relb = (const float*)d_in[5];
    float* out = (float*)d_out;

    _Float16* w1T  = (_Float16*)((char*)d_ws);
    _Float16* w2T  = (_Float16*)((char*)d_ws + WS_W2T);
    float*    b1p  = (float*)((char*)d_ws + WS_B1P);
    float*    tblP = (float*)((char*)d_ws + WS_TBL);

    swin_prep_kernel<<<210, 256, 0, stream>>>(w1, b1, w2, relb, w1T, w2T, b1p, tblP);
    swin_attn_kernel<<<4096, 256, 0, stream>>>(x, w1T, w2T, b1p, b2, tblP, out);
}